// Round 4
// baseline (328.615 us; speedup 1.0000x reference)
//
#include <hip/hip_runtime.h>
#include <hip/hip_bf16.h>
#include <cstdint>

#define D_MODEL 2048
#define D_REC   384
#define NPROJ   1152          // 3*D_REC
#define BATCH   4
#define SEQ     4096
#define M_TOTAL (BATCH*SEQ)   // 16384
#define CHUNK   64
#define NCHUNK  (SEQ/CHUNK)   // 64

// GEMM v4 geometry: 256x288 tile, grid 64x4 = 256 blocks = 1/CU exactly.
// K pipelined in half-tiles of 32 through a 4-buffer LDS ring, prefetch dist 2.
#define BM 256
#define BN 288
#define HK 32                 // half-K step
#define HT (D_MODEL/HK)       // 64 half-tiles

typedef __attribute__((ext_vector_type(8))) short  short8;
typedef __attribute__((ext_vector_type(4))) float  f32x4;

__device__ __forceinline__ float rcpf(float x) { return __builtin_amdgcn_rcpf(x); }

// ---------------------------------------------------------------- convert
__device__ __forceinline__ uint16_t f2bf(float x) {
    __hip_bfloat16 h = __float2bfloat16(x);
    return *reinterpret_cast<uint16_t*>(&h);
}

// one launch converts both x and W
__global__ void cvt_both(const float* __restrict__ x, uint16_t* __restrict__ xb,
                         const float* __restrict__ W, uint16_t* __restrict__ Wb) {
    const long nx = (long)M_TOTAL * D_MODEL;
    const long nw = (long)NPROJ * D_MODEL;
    long i = ((long)blockIdx.x * blockDim.x + threadIdx.x) * 4;
    if (i < nx) {
        float4 f = *reinterpret_cast<const float4*>(x + i);
        ushort4 o;
        o.x = f2bf(f.x); o.y = f2bf(f.y); o.z = f2bf(f.z); o.w = f2bf(f.w);
        *reinterpret_cast<ushort4*>(xb + i) = o;
    } else {
        long j = i - nx;
        if (j < nw) {
            float4 f = *reinterpret_cast<const float4*>(W + j);
            ushort4 o;
            o.x = f2bf(f.x); o.y = f2bf(f.y); o.z = f2bf(f.z); o.w = f2bf(f.w);
            *reinterpret_cast<ushort4*>(Wb + j) = o;
        }
    }
}

// ---------------------------------------------------------------- GEMM v4
// C^T[n][m] = sum_k A[m][k]*B[n][k].  8 waves (4M x 2N), per-wave 64x144.
// Pipeline: 64 half-tiles (K=32), 4-buffer LDS ring, prefetch distance 2.
// Per half-tile: stage(h+2) issue -> COUNTED s_waitcnt vmcnt(2c) (stage h
// landed, h+1/h+2 stay in flight) -> barrier -> 13 ds_read_b128 -> 36 MFMA.
// No vmcnt(0) drain in the main loop (T3+T4).  setprio around MFMA (T5).
// LDS swizzle for BK=32: G-chunk cg = c8 ^ ((rl>>1)&3); read chunk
// qq ^ ((lm>>1)&3) -> 16-lane groups cover 8 distinct 16B slots = 2-way (free).
__device__ __forceinline__ void gload_lds16(const uint16_t* g, uint16_t* l) {
    __builtin_amdgcn_global_load_lds(
        (__attribute__((address_space(1))) void*)g,
        (__attribute__((address_space(3))) void*)l,
        16, 0, 0);
}

__launch_bounds__(512, 1)
__global__ void gemm_bf16nt_v4(const uint16_t* __restrict__ A,   // [16384][2048]
                               const uint16_t* __restrict__ Bm,  // [1152][2048]
                               float* __restrict__ C)            // aivT [1152][16384]
{
    __shared__ __align__(16) uint16_t As[4][BM * HK];  // 4 x 16 KiB
    __shared__ __align__(16) uint16_t Bs[4][BN * HK];  // 4 x 18 KiB

    const int tid  = threadIdx.x;
    const int wave = tid >> 6;
    const int lane = tid & 63;
    const int m0 = blockIdx.x * BM;
    const int n0 = blockIdx.y * BN;
    const int wm = (wave >> 1) * 64;     // 4 M-waves
    const int wn = (wave & 1) * 144;     // 2 N-waves

    // ---- staging addressing: one call = 16 rows x 32 cols (64 lanes x 16B)
    const int rl = lane >> 2;                 // 0..15 row within call
    const int cg = (lane & 3) ^ ((rl >> 1) & 3);  // swizzled 16B chunk (of 4)
    // A: each wave stages rows [w*32, w*32+32) = 2 calls.
    // B: 18 calls of 16 rows; waves 0,1 own 3 calls, waves 2..7 own 2.
    const int ncb = (wave < 2) ? 3 : 2;
    const int cb0 = (wave < 2) ? wave * 3 : 6 + (wave - 2) * 2;
    const long aOff = (long)(m0 + wave * 32 + rl) * D_MODEL + cg * 8;
    const long bOff = (long)(n0 + cb0 * 16 + rl) * D_MODEL + cg * 8;

    // ---- fragment addressing
    const int lm  = lane & 15;
    const int qq  = lane >> 4;
    const int kch = (qq ^ ((lm >> 1) & 3)) * 8;   // lane-constant k-chunk (elems)

    f32x4 acc[4][9];
#pragma unroll
    for (int i = 0; i < 4; ++i)
#pragma unroll
        for (int j = 0; j < 9; ++j) acc[i][j] = (f32x4){0.f, 0.f, 0.f, 0.f};

    // ---- stage one half-tile (4 or 5 gload_lds calls per wave)
    auto stage = [&](int ht) {
        const int p = ht & 3;
        const long k0 = (long)ht * HK;
        uint16_t* ab = &As[p][(wave * 32) * HK];
        uint16_t* bb = &Bs[p][(cb0 * 16) * HK];
        gload_lds16(A + aOff + k0,                         ab);
        gload_lds16(A + aOff + k0 + (long)16 * D_MODEL,    ab + 16 * HK);
        gload_lds16(Bm + bOff + k0,                        bb);
        gload_lds16(Bm + bOff + k0 + (long)16 * D_MODEL,   bb + 16 * HK);
        if (wave < 2)
            gload_lds16(Bm + bOff + k0 + (long)32 * D_MODEL, bb + 32 * HK);
    };

    // ---- prologue: fill ring slots 0,1
    stage(0);
    stage(1);

    for (int h = 0; h < HT; ++h) {
        if (h + 2 < HT) stage(h + 2);

        // counted wait: own stage(h) landed; stage(h+1)/(h+2) stay in flight
        if (h < HT - 2) {
            if (wave < 2) asm volatile("s_waitcnt vmcnt(10)" ::: "memory");
            else          asm volatile("s_waitcnt vmcnt(8)"  ::: "memory");
        } else if (h == HT - 2) {
            if (wave < 2) asm volatile("s_waitcnt vmcnt(5)" ::: "memory");
            else          asm volatile("s_waitcnt vmcnt(4)" ::: "memory");
        } else {
            asm volatile("s_waitcnt vmcnt(0)" ::: "memory");
        }
        __builtin_amdgcn_sched_barrier(0);
        __builtin_amdgcn_s_barrier();

        const uint16_t* ap = &As[h & 3][0];
        const uint16_t* bp = &Bs[h & 3][0];

        short8 af[4], bfr[9];
#pragma unroll
        for (int mt = 0; mt < 4; ++mt)
            af[mt] = *reinterpret_cast<const short8*>(
                &ap[(wm + mt * 16 + lm) * HK + kch]);
#pragma unroll
        for (int nt = 0; nt < 9; ++nt)
            bfr[nt] = *reinterpret_cast<const short8*>(
                &bp[(wn + nt * 16 + lm) * HK + kch]);

        __builtin_amdgcn_s_setprio(1);
#pragma unroll
        for (int mt = 0; mt < 4; ++mt)
#pragma unroll
            for (int nt = 0; nt < 9; ++nt)
                acc[mt][nt] = __builtin_amdgcn_mfma_f32_16x16x32_bf16(
                    af[mt], bfr[nt], acc[mt][nt], 0, 0, 0);
        __builtin_amdgcn_s_setprio(0);
    }

    // ---- epilogue (transposed): aivT[col][row..row+3] = acc  (one float4/lane)
#pragma unroll
    for (int mt = 0; mt < 4; ++mt) {
#pragma unroll
        for (int nt = 0; nt < 9; ++nt) {
            const int row = m0 + wm + mt * 16 + qq * 4;
            const int col = n0 + wn + nt * 16 + lm;
            float4 o;
            o.x = acc[mt][nt][0]; o.y = acc[mt][nt][1];
            o.z = acc[mt][nt][2]; o.w = acc[mt][nt][3];
            *reinterpret_cast<float4*>(&C[(long)col * M_TOTAL + row]) = o;
        }
    }
}

// ---------------------------------------------------------------- intra-chunk scan (t-PARALLEL)
// One wave per (b, chunk, d): lane = t.  Prefix product of clipped decay +
// prefix sum of sig/cumdec via 6 shfl_up steps each.  Transposed layout:
// all global accesses 256B/wave contiguous.
__global__ void intra_scan_T(const float* __restrict__ aivT, const float* __restrict__ bias,
                             float* __restrict__ cumwT,   // [D_REC][M_TOTAL]
                             float* __restrict__ cumdecT, // [D_REC][M_TOTAL]
                             float* __restrict__ ctd,     // [B][NCHUNK][D]
                             float* __restrict__ cfs)     // [B][NCHUNK][D]
{
    const int w = threadIdx.x >> 6;          // 0..3
    const int t = threadIdx.x & 63;          // time step within chunk
    const int d = blockIdx.z * 4 + w;        // 0..383
    const int c = blockIdx.x;
    const int b = blockIdx.y;
    const long m = (long)b * SEQ + (long)c * CHUNK + t;

    const float ap = aivT[(long)d * M_TOTAL + m];
    const float ip = aivT[(long)(D_REC + d) * M_TOTAL + m];
    const float vv = aivT[(long)(2 * D_REC + d) * M_TOTAL + m];

    const float a   = rcpf(1.f + __expf(-(ap + bias[d])));
    const float g   = rcpf(1.f + __expf(-ip));
    const float sig = sqrtf(fmaxf(1.f - a * a, 1e-8f)) * (g * vv);

    // inclusive prefix product of clipped decay
    float cd = fmaxf(a, 1e-10f);
#pragma unroll
    for (int off = 1; off < 64; off <<= 1) {
        const float o = __shfl_up(cd, off, 64);
        cd = (t >= off) ? cd * o : cd;
    }
    // inclusive prefix sum of sig / clip(cd)
    float cw = sig * rcpf(fmaxf(cd, 1e-10f));
#pragma unroll
    for (int off = 1; off < 64; off <<= 1) {
        const float o = __shfl_up(cw, off, 64);
        cw = (t >= off) ? cw + o : cw;
    }

    cumdecT[(long)d * M_TOTAL + m] = cd;
    cumwT [(long)d * M_TOTAL + m] = cw;
    if (t == 63) {
        const long cb = ((long)b * NCHUNK + c) * D_REC + d;
        ctd[cb] = cd;
        cfs[cb] = cd * cw;
    }
}

// ---------------------------------------------------------------- cross-chunk scan
__global__ void cross_scan(const float* __restrict__ ctd, const float* __restrict__ cfs,
                           float* __restrict__ incoming)  // [B][NCHUNK][D]
{
    const int d = threadIdx.x;
    const int b = blockIdx.x;
    float cdk = 1.f, cwk = 0.f;
    incoming[(long)b * NCHUNK * D_REC + d] = 0.f;
#pragma unroll 4
    for (int c = 0; c < NCHUNK; ++c) {
        const long idx = ((long)b * NCHUNK + c) * D_REC + d;
        const float td = ctd[idx];
        const float fs = cfs[idx];
        cdk *= fmaxf(td, 1e-10f);
        cwk += fs * rcpf(fmaxf(cdk, 1e-10f));
        if (c + 1 < NCHUNK) incoming[idx + D_REC] = cdk * cwk;
    }
}

// ---------------------------------------------------------------- final combine + transpose
// out[b][s][d] = cumdecT[d][m] * (cumwT[d][m] + inc[m/64][d]),  m = b*4096+s.
// 64x64 tile through padded LDS: reads coalesced in m, writes coalesced in d.
__global__ void final_combine_T(const float* __restrict__ cumdecT, const float* __restrict__ cumwT,
                                const float* __restrict__ inc, float* __restrict__ out)
{
    __shared__ float tile[64][65];
    const int m0 = blockIdx.x * 64;            // 256 tiles over m (one chunk each)
    const int d0 = blockIdx.y * 64;            // 6 tiles over d
    const long incBase = (long)(m0 >> 6) * D_REC + d0;   // (b*64+c)*384 + d0

#pragma unroll
    for (int i = 0; i < 16; ++i) {
        const int flat = threadIdx.x + i * 256;
        const int dd = flat >> 6, ss = flat & 63;
        const long src = (long)(d0 + dd) * M_TOTAL + m0 + ss;
        tile[dd][ss] = cumdecT[src] * (cumwT[src] + inc[incBase + dd]);
    }
    __syncthreads();
#pragma unroll
    for (int i = 0; i < 16; ++i) {
        const int flat = threadIdx.x + i * 256;
        const int ss = flat >> 6, dd = flat & 63;
        out[(long)(m0 + ss) * D_REC + d0 + dd] = tile[dd][ss];
    }
}

// ---------------------------------------------------------------- launch
extern "C" void kernel_launch(void* const* d_in, const int* in_sizes, int n_in,
                              void* d_out, int out_size, void* d_ws, size_t ws_size,
                              hipStream_t stream) {
    const float* x  = (const float*)d_in[0];   // [4][4096][2048]
    const float* W  = (const float*)d_in[1];   // [1152][2048]
    const float* db = (const float*)d_in[2];   // [384]
    float* out = (float*)d_out;                // [4][4096][384]

    char* ws = (char*)d_ws;
    // layout (bytes): aivT 75.5MB | xb 64MB (dead after GEMM; cumdecT+cumwT overlay) | Wb 4.5MB
    float*    aivT    = (float*)   (ws + 0);                 // 75,497,472 B  [1152][16384]
    uint16_t* xb      = (uint16_t*)(ws + 75497472L);         // 67,108,864 B
    uint16_t* Wb      = (uint16_t*)(ws + 142606336L);        //  4,718,592 B
    float*    cumdecT = (float*)   (ws + 75497472L);         // 25,165,824 B (overlays xb)
    float*    cumwT   = (float*)   (ws + 100663296L);        // 25,165,824 B (overlays xb)
    float*    ctd     = (float*)   (ws + 125829120L);        //    393,216 B
    float*    cfs     = (float*)   (ws + 126222336L);        //    393,216 B
    float*    inc     = (float*)   (ws + 126615552L);        //    393,216 B

    // 1. convert x and W to bf16 (single launch)
    {
        const long ntot = (long)M_TOTAL * D_MODEL + (long)NPROJ * D_MODEL;
        cvt_both<<<(int)((ntot + 1023) / 1024), 256, 0, stream>>>(x, xb, W, Wb);
    }

    // 2. aivT = (x . W^T)^T via bf16 MFMA (counted-vmcnt ring pipeline)
    gemm_bf16nt_v4<<<dim3(M_TOTAL / BM, NPROJ / BN), 512, 0, stream>>>(xb, Wb, aivT);

    // 3. intra-chunk scan, wave-parallel over t (one wave per (b,c,d))
    intra_scan_T<<<dim3(NCHUNK, BATCH, D_REC / 4), 256, 0, stream>>>(aivT, db, cumwT, cumdecT, ctd, cfs);

    // 4. cross-chunk scan
    cross_scan<<<BATCH, D_REC, 0, stream>>>(ctd, cfs, inc);

    // 5. combine + transpose back to [B][S][D]
    final_combine_T<<<dim3(M_TOTAL / 64, D_REC / 64), 256, 0, stream>>>(cumdecT, cumwT, inc, out);
}

// Round 6
// 326.403 us; speedup vs baseline: 1.0068x; 1.0068x over previous
//
#include <hip/hip_runtime.h>
#include <hip/hip_bf16.h>
#include <cstdint>

#define D_MODEL 2048
#define D_REC   384
#define NPROJ   1152          // 3*D_REC
#define BATCH   4
#define SEQ     4096
#define M_TOTAL (BATCH*SEQ)   // 16384
#define CHUNK   64
#define NCHUNK  (SEQ/CHUNK)   // 64

// GEMM v6 geometry: 128x288 tile, grid 128x4 = 512 blocks = exactly 2/CU
// co-resident (LDS 78KB, <=256 regs).  Two independent blocks per CU
// anti-phase: one block's LDS-read phase overlaps the other's MFMA phase.
#define BM 128
#define BN 288
#define HK 32                 // half-K step
#define HT (D_MODEL/HK)       // 64 half-tiles

typedef __attribute__((ext_vector_type(8))) short  short8;
typedef __attribute__((ext_vector_type(4))) float  f32x4;

__device__ __forceinline__ float rcpf(float x) { return __builtin_amdgcn_rcpf(x); }

// ---------------------------------------------------------------- convert
__device__ __forceinline__ uint16_t f2bf(float x) {
    __hip_bfloat16 h = __float2bfloat16(x);
    return *reinterpret_cast<uint16_t*>(&h);
}

// one launch converts both x and W
__global__ void cvt_both(const float* __restrict__ x, uint16_t* __restrict__ xb,
                         const float* __restrict__ W, uint16_t* __restrict__ Wb) {
    const long nx = (long)M_TOTAL * D_MODEL;
    const long nw = (long)NPROJ * D_MODEL;
    long i = ((long)blockIdx.x * blockDim.x + threadIdx.x) * 4;
    if (i < nx) {
        float4 f = *reinterpret_cast<const float4*>(x + i);
        ushort4 o;
        o.x = f2bf(f.x); o.y = f2bf(f.y); o.z = f2bf(f.z); o.w = f2bf(f.w);
        *reinterpret_cast<ushort4*>(xb + i) = o;
    } else {
        long j = i - nx;
        if (j < nw) {
            float4 f = *reinterpret_cast<const float4*>(W + j);
            ushort4 o;
            o.x = f2bf(f.x); o.y = f2bf(f.y); o.z = f2bf(f.z); o.w = f2bf(f.w);
            *reinterpret_cast<ushort4*>(Wb + j) = o;
        }
    }
}

// ---------------------------------------------------------------- GEMM v6
// C^T[n][m] = sum_k A[m][k]*B[n][k].  4 waves (2M x 2N), per-wave 64x144
// (frag/acc/swizzle layout identical to harness-verified v4 wave code).
// Ring-3 LDS pipeline with RACE-FREE ordering (v5 post-mortem):
//   phase h: counted vmcnt(stage h landed) -> barrier A -> ds_reads slot h%3
//            -> lgkmcnt(0) -> barrier B (reads complete BLOCK-WIDE)
//            -> stage(h+2) issue (overwrites slot (h-1)%3: safe, its reads
//               were barrier-B'd at phase h-1) -> MFMA cluster.
// Counted wait never drains to 0 mid-loop (only stage(h+1) stays in flight).
__device__ __forceinline__ void gload_lds16(const uint16_t* g, uint16_t* l) {
    __builtin_amdgcn_global_load_lds(
        (__attribute__((address_space(1))) void*)g,
        (__attribute__((address_space(3))) void*)l,
        16, 0, 0);
}

__launch_bounds__(256, 2)
__global__ void gemm_bf16nt_v6(const uint16_t* __restrict__ A,   // [16384][2048]
                               const uint16_t* __restrict__ Bm,  // [1152][2048]
                               float* __restrict__ C)            // aivT [1152][16384]
{
    __shared__ __align__(16) uint16_t As[3][BM * HK];  // 3 x 8 KiB
    __shared__ __align__(16) uint16_t Bs[3][BN * HK];  // 3 x 18 KiB

    const int tid  = threadIdx.x;
    const int wave = tid >> 6;           // 0..3
    const int lane = tid & 63;
    const int m0 = blockIdx.x * BM;
    const int n0 = blockIdx.y * BN;
    const int wm = (wave >> 1) * 64;     // 2 M-waves
    const int wn = (wave & 1) * 144;     // 2 N-waves

    // ---- staging addressing: one call = 16 rows x 32 cols (64 lanes x 16B)
    const int rl = lane >> 2;                     // 0..15 row within call
    const int cg = (lane & 3) ^ ((rl >> 1) & 3);  // swizzled 16B chunk (of 4)
    // A: 8 calls of 16 rows; wave w owns rows w*32..w*32+31 (2 calls).
    // B: 18 calls of 16 rows; waves own 5,5,4,4 calls.
    const int cb0 = (wave < 2) ? wave * 5 : 10 + (wave - 2) * 4;
    const long aOff = (long)(m0 + wave * 32 + rl) * D_MODEL + cg * 8;
    const long bOff = (long)(n0 + cb0 * 16 + rl) * D_MODEL + cg * 8;

    // ---- fragment addressing (identical to v4)
    const int lm  = lane & 15;
    const int qq  = lane >> 4;
    const int kch = (qq ^ ((lm >> 1) & 3)) * 8;   // lane-constant k-chunk (elems)

    f32x4 acc[4][9];
#pragma unroll
    for (int i = 0; i < 4; ++i)
#pragma unroll
        for (int j = 0; j < 9; ++j) acc[i][j] = (f32x4){0.f, 0.f, 0.f, 0.f};

    // ---- stage one half-tile (7 calls for waves 0,1; 6 for waves 2,3)
    auto stage = [&](int ht) {
        const int p = ht % 3;
        const long k0 = (long)ht * HK;
        uint16_t* ab = &As[p][(wave * 32) * HK];
        uint16_t* bb = &Bs[p][(cb0 * 16) * HK];
        gload_lds16(A + aOff + k0,                          ab);
        gload_lds16(A + aOff + k0 + (long)16 * D_MODEL,     ab + 16 * HK);
        gload_lds16(Bm + bOff + k0,                         bb);
        gload_lds16(Bm + bOff + k0 + (long)16 * D_MODEL,    bb + 16 * HK);
        gload_lds16(Bm + bOff + k0 + (long)32 * D_MODEL,    bb + 32 * HK);
        gload_lds16(Bm + bOff + k0 + (long)48 * D_MODEL,    bb + 48 * HK);
        if (wave < 2)
            gload_lds16(Bm + bOff + k0 + (long)64 * D_MODEL, bb + 64 * HK);
    };

    // ---- prologue: fill ring slots 0,1
    stage(0);
    stage(1);

    for (int h = 0; h < HT; ++h) {
        // 1. counted wait: own stage(h) landed; stage(h+1) stays in flight
        if (h < HT - 1) {
            if (wave < 2) asm volatile("s_waitcnt vmcnt(7)" ::: "memory");
            else          asm volatile("s_waitcnt vmcnt(6)" ::: "memory");
        } else {
            asm volatile("s_waitcnt vmcnt(0)" ::: "memory");
        }
        __builtin_amdgcn_sched_barrier(0);
        __builtin_amdgcn_s_barrier();          // A: stage(h) visible block-wide

        // 2. fragment reads from slot h%3
        const uint16_t* ap = &As[h % 3][0];
        const uint16_t* bp = &Bs[h % 3][0];
        short8 af[4], bfr[9];
#pragma unroll
        for (int mt = 0; mt < 4; ++mt)
            af[mt] = *reinterpret_cast<const short8*>(
                &ap[(wm + mt * 16 + lm) * HK + kch]);
#pragma unroll
        for (int nt = 0; nt < 9; ++nt)
            bfr[nt] = *reinterpret_cast<const short8*>(
                &bp[(wn + nt * 16 + lm) * HK + kch]);

        asm volatile("s_waitcnt lgkmcnt(0)" ::: "memory");
        __builtin_amdgcn_sched_barrier(0);
        __builtin_amdgcn_s_barrier();          // B: slot h%3 reads done block-wide
        __builtin_amdgcn_sched_barrier(0);

        // 3. prefetch stage(h+2) -> slot (h+2)%3 (== (h-1)%3, freed by barrier B
        //    of phase h-1; this wave is past that barrier via barrier A above)
        if (h + 2 < HT) stage(h + 2);

        // 4. MFMA cluster
        __builtin_amdgcn_s_setprio(1);
#pragma unroll
        for (int mt = 0; mt < 4; ++mt)
#pragma unroll
            for (int nt = 0; nt < 9; ++nt)
                acc[mt][nt] = __builtin_amdgcn_mfma_f32_16x16x32_bf16(
                    af[mt], bfr[nt], acc[mt][nt], 0, 0, 0);
        __builtin_amdgcn_s_setprio(0);
    }

    // ---- epilogue (transposed): aivT[col][row..row+3] = acc  (one float4/lane)
#pragma unroll
    for (int mt = 0; mt < 4; ++mt) {
#pragma unroll
        for (int nt = 0; nt < 9; ++nt) {
            const int row = m0 + wm + mt * 16 + qq * 4;
            const int col = n0 + wn + nt * 16 + lm;
            float4 o;
            o.x = acc[mt][nt][0]; o.y = acc[mt][nt][1];
            o.z = acc[mt][nt][2]; o.w = acc[mt][nt][3];
            *reinterpret_cast<float4*>(&C[(long)col * M_TOTAL + row]) = o;
        }
    }
}

// ---------------------------------------------------------------- intra-chunk scan (t-PARALLEL)
// One wave per (b, chunk, d): lane = t.  Prefix product of clipped decay +
// prefix sum of sig/cumdec via 6 shfl_up steps each.  Transposed layout:
// all global accesses 256B/wave contiguous.
__global__ void intra_scan_T(const float* __restrict__ aivT, const float* __restrict__ bias,
                             float* __restrict__ cumwT,   // [D_REC][M_TOTAL]
                             float* __restrict__ cumdecT, // [D_REC][M_TOTAL]
                             float* __restrict__ ctd,     // [B][NCHUNK][D]
                             float* __restrict__ cfs)     // [B][NCHUNK][D]
{
    const int w = threadIdx.x >> 6;          // 0..3
    const int t = threadIdx.x & 63;          // time step within chunk
    const int d = blockIdx.z * 4 + w;        // 0..383
    const int c = blockIdx.x;
    const int b = blockIdx.y;
    const long m = (long)b * SEQ + (long)c * CHUNK + t;

    const float ap = aivT[(long)d * M_TOTAL + m];
    const float ip = aivT[(long)(D_REC + d) * M_TOTAL + m];
    const float vv = aivT[(long)(2 * D_REC + d) * M_TOTAL + m];

    const float a   = rcpf(1.f + __expf(-(ap + bias[d])));
    const float g   = rcpf(1.f + __expf(-ip));
    const float sig = sqrtf(fmaxf(1.f - a * a, 1e-8f)) * (g * vv);

    // inclusive prefix product of clipped decay
    float cd = fmaxf(a, 1e-10f);
#pragma unroll
    for (int off = 1; off < 64; off <<= 1) {
        const float o = __shfl_up(cd, off, 64);
        cd = (t >= off) ? cd * o : cd;
    }
    // inclusive prefix sum of sig / clip(cd)
    float cw = sig * rcpf(fmaxf(cd, 1e-10f));
#pragma unroll
    for (int off = 1; off < 64; off <<= 1) {
        const float o = __shfl_up(cw, off, 64);
        cw = (t >= off) ? cw + o : cw;
    }

    cumdecT[(long)d * M_TOTAL + m] = cd;
    cumwT [(long)d * M_TOTAL + m] = cw;
    if (t == 63) {
        const long cb = ((long)b * NCHUNK + c) * D_REC + d;
        ctd[cb] = cd;
        cfs[cb] = cd * cw;
    }
}

// ---------------------------------------------------------------- cross-chunk scan
__global__ void cross_scan(const float* __restrict__ ctd, const float* __restrict__ cfs,
                           float* __restrict__ incoming)  // [B][NCHUNK][D]
{
    const int d = threadIdx.x;
    const int b = blockIdx.x;
    float cdk = 1.f, cwk = 0.f;
    incoming[(long)b * NCHUNK * D_REC + d] = 0.f;
#pragma unroll 4
    for (int c = 0; c < NCHUNK; ++c) {
        const long idx = ((long)b * NCHUNK + c) * D_REC + d;
        const float td = ctd[idx];
        const float fs = cfs[idx];
        cdk *= fmaxf(td, 1e-10f);
        cwk += fs * rcpf(fmaxf(cdk, 1e-10f));
        if (c + 1 < NCHUNK) incoming[idx + D_REC] = cdk * cwk;
    }
}

// ---------------------------------------------------------------- final combine + transpose
// out[b][s][d] = cumdecT[d][m] * (cumwT[d][m] + inc[m/64][d]),  m = b*4096+s.
// 64x64 tile through padded LDS: reads coalesced in m, writes coalesced in d.
__global__ void final_combine_T(const float* __restrict__ cumdecT, const float* __restrict__ cumwT,
                                const float* __restrict__ inc, float* __restrict__ out)
{
    __shared__ float tile[64][65];
    const int m0 = blockIdx.x * 64;            // 256 tiles over m (one chunk each)
    const int d0 = blockIdx.y * 64;            // 6 tiles over d
    const long incBase = (long)(m0 >> 6) * D_REC + d0;   // (b*64+c)*384 + d0

#pragma unroll
    for (int i = 0; i < 16; ++i) {
        const int flat = threadIdx.x + i * 256;
        const int dd = flat >> 6, ss = flat & 63;
        const long src = (long)(d0 + dd) * M_TOTAL + m0 + ss;
        tile[dd][ss] = cumdecT[src] * (cumwT[src] + inc[incBase + dd]);
    }
    __syncthreads();
#pragma unroll
    for (int i = 0; i < 16; ++i) {
        const int flat = threadIdx.x + i * 256;
        const int ss = flat >> 6, dd = flat & 63;
        out[(long)(m0 + ss) * D_REC + d0 + dd] = tile[dd][ss];
    }
}

// ---------------------------------------------------------------- launch
extern "C" void kernel_launch(void* const* d_in, const int* in_sizes, int n_in,
                              void* d_out, int out_size, void* d_ws, size_t ws_size,
                              hipStream_t stream) {
    const float* x  = (const float*)d_in[0];   // [4][4096][2048]
    const float* W  = (const float*)d_in[1];   // [1152][2048]
    const float* db = (const float*)d_in[2];   // [384]
    float* out = (float*)d_out;                // [4][4096][384]

    char* ws = (char*)d_ws;
    // layout (bytes): aivT 75.5MB | xb 64MB (dead after GEMM; cumdecT+cumwT overlay) | Wb 4.5MB
    float*    aivT    = (float*)   (ws + 0);                 // 75,497,472 B  [1152][16384]
    uint16_t* xb      = (uint16_t*)(ws + 75497472L);         // 67,108,864 B
    uint16_t* Wb      = (uint16_t*)(ws + 142606336L);        //  4,718,592 B
    float*    cumdecT = (float*)   (ws + 75497472L);         // 25,165,824 B (overlays xb)
    float*    cumwT   = (float*)   (ws + 100663296L);        // 25,165,824 B (overlays xb)
    float*    ctd     = (float*)   (ws + 125829120L);        //    393,216 B
    float*    cfs     = (float*)   (ws + 126222336L);        //    393,216 B
    float*    inc     = (float*)   (ws + 126615552L);        //    393,216 B

    // 1. convert x and W to bf16 (single launch)
    {
        const long ntot = (long)M_TOTAL * D_MODEL + (long)NPROJ * D_MODEL;
        cvt_both<<<(int)((ntot + 1023) / 1024), 256, 0, stream>>>(x, xb, W, Wb);
    }

    // 2. aivT = (x . W^T)^T via bf16 MFMA (128x288 tile, 2 blocks/CU anti-phased)
    gemm_bf16nt_v6<<<dim3(M_TOTAL / BM, NPROJ / BN), 256, 0, stream>>>(xb, Wb, aivT);

    // 3. intra-chunk scan, wave-parallel over t (one wave per (b,c,d))
    intra_scan_T<<<dim3(NCHUNK, BATCH, D_REC / 4), 256, 0, stream>>>(aivT, db, cumwT, cumdecT, ctd, cfs);

    // 4. cross-chunk scan
    cross_scan<<<BATCH, D_REC, 0, stream>>>(ctd, cfs, inc);

    // 5. combine + transpose back to [B][S][D]
    final_combine_T<<<dim3(M_TOTAL / 64, D_REC / 64), 256, 0, stream>>>(cumdecT, cumwT, inc, out);
}

// Round 7
// 324.229 us; speedup vs baseline: 1.0135x; 1.0067x over previous
//
#include <hip/hip_runtime.h>
#include <hip/hip_bf16.h>
#include <cstdint>

#define D_MODEL 2048
#define D_REC   384
#define NPROJ   1152          // 3*D_REC
#define BATCH   4
#define SEQ     4096
#define M_TOTAL (BATCH*SEQ)   // 16384
#define CHUNK   64
#define NCHUNK  (SEQ/CHUNK)   // 64

// GEMM v7 geometry: 128x288 tile, grid 128x4 = 512 blocks = 2/CU co-resident.
// A is consumed directly as f32 (x) with in-kernel bf16 conversion during
// reg-staging -> the 215MB cvt_both kernel is eliminated from the pipeline.
#define BM 128
#define BN 288
#define HK 32                 // K step
#define HT (D_MODEL/HK)       // 64 tiles

typedef __attribute__((ext_vector_type(8))) short  short8;
typedef __attribute__((ext_vector_type(4))) float  f32x4;

__device__ __forceinline__ float rcpf(float x) { return __builtin_amdgcn_rcpf(x); }

__device__ __forceinline__ uint16_t f2bf(float x) {
    __hip_bfloat16 h = __float2bfloat16(x);
    return *reinterpret_cast<uint16_t*>(&h);
}

// ---------------------------------------------------------------- convert W only (9.4 MB)
__global__ void cvt_w(const float* __restrict__ W, uint16_t* __restrict__ Wb) {
    long i = ((long)blockIdx.x * blockDim.x + threadIdx.x) * 4;
    float4 f = *reinterpret_cast<const float4*>(W + i);
    ushort4 o;
    o.x = f2bf(f.x); o.y = f2bf(f.y); o.z = f2bf(f.z); o.w = f2bf(f.w);
    *reinterpret_cast<ushort4*>(Wb + i) = o;
}

// ---------------------------------------------------------------- GEMM v7
// C^T[n][m] = sum_k A[m][k]*B[n][k].  4 waves (2M x 2N), per-wave 64x144
// (fragment/acc/epilogue code identical to harness-verified v6).
// A: f32 source, reg-staged (4x global_load_dwordx4 -> 16x cvt -> 2x
//    ds_write_b128 at XOR-swizzled chunks, key (row>>1)&3 == read-side kch).
// B: bf16 source via global_load_lds with pre-swizzled global address (v6).
// Double-buffered; per phase: issue A-loads+B-gloads for h+1 -> frags(h) ->
// MFMA -> sched_barrier -> cvt+ds_write A(h+1) (auto counted vmcnt wait; B
// stays in flight under it) -> __syncthreads (drains B + ds_writes).
__device__ __forceinline__ void gload_lds16(const uint16_t* g, uint16_t* l) {
    __builtin_amdgcn_global_load_lds(
        (__attribute__((address_space(1))) void*)g,
        (__attribute__((address_space(3))) void*)l,
        16, 0, 0);
}

__launch_bounds__(256, 2)
__global__ void gemm_f32a_v7(const float* __restrict__ Af,    // x [16384][2048] f32
                             const uint16_t* __restrict__ Bm, // W [1152][2048] bf16
                             float* __restrict__ C)           // aivT [1152][16384]
{
    __shared__ __align__(16) uint16_t As[2][BM * HK];  // 2 x 8 KiB
    __shared__ __align__(16) uint16_t Bs[2][BN * HK];  // 2 x 18 KiB

    const int tid  = threadIdx.x;
    const int wave = tid >> 6;           // 0..3
    const int lane = tid & 63;
    const int m0 = blockIdx.x * BM;
    const int n0 = blockIdx.y * BN;
    const int wm = (wave >> 1) * 64;     // 2 M-waves
    const int wn = (wave & 1) * 144;     // 2 N-waves

    // ---- A staging: thread -> (row 0..127, 16-col half)
    const int arow  = tid >> 1;
    const int ahalf = tid & 1;
    const int akey  = (arow >> 1) & 3;
    const float* aSrc = Af + (long)(m0 + arow) * D_MODEL + ahalf * 16;
    const int aw0 = arow * HK + (((ahalf * 2)    ) ^ akey) * 8;
    const int aw1 = arow * HK + (((ahalf * 2) + 1) ^ akey) * 8;

    // ---- B staging (identical to v6): 18 calls of 16 rows; waves own 5,5,4,4
    const int rl = lane >> 2;
    const int cg = (lane & 3) ^ ((rl >> 1) & 3);
    const int cb0 = (wave < 2) ? wave * 5 : 10 + (wave - 2) * 4;
    const long bOff = (long)(n0 + cb0 * 16 + rl) * D_MODEL + cg * 8;

    // ---- fragment addressing (identical to v6)
    const int lm  = lane & 15;
    const int qq  = lane >> 4;
    const int kch = (qq ^ ((lm >> 1) & 3)) * 8;

    f32x4 acc[4][9];
#pragma unroll
    for (int i = 0; i < 4; ++i)
#pragma unroll
        for (int j = 0; j < 9; ++j) acc[i][j] = (f32x4){0.f, 0.f, 0.f, 0.f};

    auto stageB = [&](int ht, int slot) {
        const long k0 = (long)ht * HK;
        uint16_t* bb = &Bs[slot][(cb0 * 16) * HK];
        gload_lds16(Bm + bOff + k0,                          bb);
        gload_lds16(Bm + bOff + k0 + (long)16 * D_MODEL,     bb + 16 * HK);
        gload_lds16(Bm + bOff + k0 + (long)32 * D_MODEL,     bb + 32 * HK);
        gload_lds16(Bm + bOff + k0 + (long)48 * D_MODEL,     bb + 48 * HK);
        if (wave < 2) {
            gload_lds16(Bm + bOff + k0 + (long)64 * D_MODEL, bb + 64 * HK);
        }
    };
    // waves 0,1 have 5 B-calls (cb0*16 rows .. +80); waves 2,3 have 4.
    auto stageB2 = [&](int ht, int slot) {
        const long k0 = (long)ht * HK;
        uint16_t* bb = &Bs[slot][(cb0 * 16) * HK];
        if (wave < 2)
            gload_lds16(Bm + bOff + k0 + (long)48 * D_MODEL, bb + 48 * HK);
    };
    (void)stageB2;

    auto cvtWrite = [&](const float4* av, int slot) {
        short8 w0, w1;
        w0[0] = (short)f2bf(av[0].x); w0[1] = (short)f2bf(av[0].y);
        w0[2] = (short)f2bf(av[0].z); w0[3] = (short)f2bf(av[0].w);
        w0[4] = (short)f2bf(av[1].x); w0[5] = (short)f2bf(av[1].y);
        w0[6] = (short)f2bf(av[1].z); w0[7] = (short)f2bf(av[1].w);
        w1[0] = (short)f2bf(av[2].x); w1[1] = (short)f2bf(av[2].y);
        w1[2] = (short)f2bf(av[2].z); w1[3] = (short)f2bf(av[2].w);
        w1[4] = (short)f2bf(av[3].x); w1[5] = (short)f2bf(av[3].y);
        w1[6] = (short)f2bf(av[3].z); w1[7] = (short)f2bf(av[3].w);
        *reinterpret_cast<short8*>(&As[slot][aw0]) = w0;
        *reinterpret_cast<short8*>(&As[slot][aw1]) = w1;
    };

    // ---- prologue: tile 0 into slot 0
    {
        float4 av[4];
#pragma unroll
        for (int j = 0; j < 4; ++j)
            av[j] = *reinterpret_cast<const float4*>(aSrc + j * 4);
        stageB(0, 0);
        cvtWrite(av, 0);
    }
    __syncthreads();

    for (int h = 0; h < HT; ++h) {
        const int cur = h & 1;
        const bool pf = (h + 1) < HT;
        float4 av[4];
        if (pf) {
            const long k0n = (long)(h + 1) * HK;
#pragma unroll
            for (int j = 0; j < 4; ++j)
                av[j] = *reinterpret_cast<const float4*>(aSrc + k0n + j * 4);
            stageB(h + 1, cur ^ 1);
            __builtin_amdgcn_sched_barrier(0);
        }

        const uint16_t* ap = &As[cur][0];
        const uint16_t* bp = &Bs[cur][0];

        short8 af[4];
#pragma unroll
        for (int mt = 0; mt < 4; ++mt)
            af[mt] = *reinterpret_cast<const short8*>(
                &ap[(wm + mt * 16 + lm) * HK + kch]);

        __builtin_amdgcn_s_setprio(1);
#pragma unroll
        for (int g = 0; g < 3; ++g) {          // grouped B-frags: 12 VGPR not 36
            short8 bfr[3];
#pragma unroll
            for (int nt = 0; nt < 3; ++nt)
                bfr[nt] = *reinterpret_cast<const short8*>(
                    &bp[(wn + (g * 3 + nt) * 16 + lm) * HK + kch]);
#pragma unroll
            for (int mt = 0; mt < 4; ++mt)
#pragma unroll
                for (int nt = 0; nt < 3; ++nt)
                    acc[mt][g * 3 + nt] = __builtin_amdgcn_mfma_f32_16x16x32_bf16(
                        af[mt], bfr[nt], acc[mt][g * 3 + nt], 0, 0, 0);
        }
        __builtin_amdgcn_s_setprio(0);

        if (pf) {
            __builtin_amdgcn_sched_barrier(0);
            // auto s_waitcnt vmcnt(N) here waits only the 4 A-loads (oldest);
            // B gload_lds stay in flight until the __syncthreads drain.
            cvtWrite(av, cur ^ 1);
            __syncthreads();
        }
    }

    // ---- epilogue (transposed): aivT[col][row..row+3] = acc  (one float4/lane)
#pragma unroll
    for (int mt = 0; mt < 4; ++mt) {
#pragma unroll
        for (int nt = 0; nt < 9; ++nt) {
            const int row = m0 + wm + mt * 16 + qq * 4;
            const int col = n0 + wn + nt * 16 + lm;
            float4 o;
            o.x = acc[mt][nt][0]; o.y = acc[mt][nt][1];
            o.z = acc[mt][nt][2]; o.w = acc[mt][nt][3];
            *reinterpret_cast<float4*>(&C[(long)col * M_TOTAL + row]) = o;
        }
    }
}

// ---------------------------------------------------------------- intra-chunk scan (t-PARALLEL)
__global__ void intra_scan_T(const float* __restrict__ aivT, const float* __restrict__ bias,
                             float* __restrict__ cumwT,   // [D_REC][M_TOTAL]
                             float* __restrict__ cumdecT, // [D_REC][M_TOTAL]
                             float* __restrict__ ctd,     // [B][NCHUNK][D]
                             float* __restrict__ cfs)     // [B][NCHUNK][D]
{
    const int w = threadIdx.x >> 6;          // 0..3
    const int t = threadIdx.x & 63;          // time step within chunk
    const int d = blockIdx.z * 4 + w;        // 0..383
    const int c = blockIdx.x;
    const int b = blockIdx.y;
    const long m = (long)b * SEQ + (long)c * CHUNK + t;

    const float ap = aivT[(long)d * M_TOTAL + m];
    const float ip = aivT[(long)(D_REC + d) * M_TOTAL + m];
    const float vv = aivT[(long)(2 * D_REC + d) * M_TOTAL + m];

    const float a   = rcpf(1.f + __expf(-(ap + bias[d])));
    const float g   = rcpf(1.f + __expf(-ip));
    const float sig = sqrtf(fmaxf(1.f - a * a, 1e-8f)) * (g * vv);

    float cd = fmaxf(a, 1e-10f);
#pragma unroll
    for (int off = 1; off < 64; off <<= 1) {
        const float o = __shfl_up(cd, off, 64);
        cd = (t >= off) ? cd * o : cd;
    }
    float cw = sig * rcpf(fmaxf(cd, 1e-10f));
#pragma unroll
    for (int off = 1; off < 64; off <<= 1) {
        const float o = __shfl_up(cw, off, 64);
        cw = (t >= off) ? cw + o : cw;
    }

    cumdecT[(long)d * M_TOTAL + m] = cd;
    cumwT [(long)d * M_TOTAL + m] = cw;
    if (t == 63) {
        const long cb = ((long)b * NCHUNK + c) * D_REC + d;
        ctd[cb] = cd;
        cfs[cb] = cd * cw;
    }
}

// ---------------------------------------------------------------- cross-chunk scan
__global__ void cross_scan(const float* __restrict__ ctd, const float* __restrict__ cfs,
                           float* __restrict__ incoming)  // [B][NCHUNK][D]
{
    const int d = threadIdx.x;
    const int b = blockIdx.x;
    float cdk = 1.f, cwk = 0.f;
    incoming[(long)b * NCHUNK * D_REC + d] = 0.f;
#pragma unroll 4
    for (int c = 0; c < NCHUNK; ++c) {
        const long idx = ((long)b * NCHUNK + c) * D_REC + d;
        const float td = ctd[idx];
        const float fs = cfs[idx];
        cdk *= fmaxf(td, 1e-10f);
        cwk += fs * rcpf(fmaxf(cdk, 1e-10f));
        if (c + 1 < NCHUNK) incoming[idx + D_REC] = cdk * cwk;
    }
}

// ---------------------------------------------------------------- final combine + transpose
__global__ void final_combine_T(const float* __restrict__ cumdecT, const float* __restrict__ cumwT,
                                const float* __restrict__ inc, float* __restrict__ out)
{
    __shared__ float tile[64][65];
    const int m0 = blockIdx.x * 64;            // 256 tiles over m (one chunk each)
    const int d0 = blockIdx.y * 64;            // 6 tiles over d
    const long incBase = (long)(m0 >> 6) * D_REC + d0;   // (b*64+c)*384 + d0

#pragma unroll
    for (int i = 0; i < 16; ++i) {
        const int flat = threadIdx.x + i * 256;
        const int dd = flat >> 6, ss = flat & 63;
        const long src = (long)(d0 + dd) * M_TOTAL + m0 + ss;
        tile[dd][ss] = cumdecT[src] * (cumwT[src] + inc[incBase + dd]);
    }
    __syncthreads();
#pragma unroll
    for (int i = 0; i < 16; ++i) {
        const int flat = threadIdx.x + i * 256;
        const int ss = flat >> 6, dd = flat & 63;
        out[(long)(m0 + ss) * D_REC + d0 + dd] = tile[dd][ss];
    }
}

// ---------------------------------------------------------------- launch
extern "C" void kernel_launch(void* const* d_in, const int* in_sizes, int n_in,
                              void* d_out, int out_size, void* d_ws, size_t ws_size,
                              hipStream_t stream) {
    const float* x  = (const float*)d_in[0];   // [4][4096][2048]
    const float* W  = (const float*)d_in[1];   // [1152][2048]
    const float* db = (const float*)d_in[2];   // [384]
    float* out = (float*)d_out;                // [4][4096][384]

    char* ws = (char*)d_ws;
    // layout (bytes): aivT 75.5MB | Wb 4.5MB | cumdecT 25.2 | cumwT 25.2 | ctd/cfs/inc
    float*    aivT    = (float*)   (ws + 0);                 // 75,497,472 B  [1152][16384]
    uint16_t* Wb      = (uint16_t*)(ws + 75497472L);         //  4,718,592 B
    float*    cumdecT = (float*)   (ws + 80216064L);         // 25,165,824 B
    float*    cumwT   = (float*)   (ws + 105381888L);        // 25,165,824 B
    float*    ctd     = (float*)   (ws + 130547712L);        //    393,216 B
    float*    cfs     = (float*)   (ws + 130940928L);        //    393,216 B
    float*    inc     = (float*)   (ws + 131334144L);        //    393,216 B

    // 1. convert W only (x is consumed as f32 by the GEMM)
    cvt_w<<<(int)((long)NPROJ * D_MODEL / (4 * 256)), 256, 0, stream>>>(W, Wb);

    // 2. aivT = (x . W^T)^T via bf16 MFMA, f32 A converted in-staging
    gemm_f32a_v7<<<dim3(M_TOTAL / BM, NPROJ / BN), 256, 0, stream>>>(x, Wb, aivT);

    // 3. intra-chunk scan, wave-parallel over t (one wave per (b,c,d))
    intra_scan_T<<<dim3(NCHUNK, BATCH, D_REC / 4), 256, 0, stream>>>(aivT, db, cumwT, cumdecT, ctd, cfs);

    // 4. cross-chunk scan
    cross_scan<<<BATCH, D_REC, 0, stream>>>(ctd, cfs, inc);

    // 5. combine + transpose back to [B][S][D]
    final_combine_T<<<dim3(M_TOTAL / 64, D_REC / 64), 256, 0, stream>>>(cumdecT, cumwT, inc, out);
}